// Round 4
// baseline (960.659 us; speedup 1.0000x reference)
//
#include <hip/hip_runtime.h>
#include <math.h>

namespace {
constexpr int kNE = 512;          // num codebook entries
constexpr int kED = 64;           // embed dim
constexpr int kHW = 4096;         // 64*64 spatial
constexpr int kNTiles = 2048;     // 64-token tiles
constexpr int kNTok = 131072;
constexpr int kTokPerBlk = 64;
constexpr int kThreads = 256;

// output float offsets (return order: loss, out, perplexity, encodings,
// new_embedding, cluster, new_ema_w)
constexpr size_t O_LOSS    = 0;
constexpr size_t O_OUT     = 1;
constexpr size_t O_PERP    = 8388609;
constexpr size_t O_ENC     = 8388610;   // byte-align 8 (float2 ok, float4 NOT)
constexpr size_t O_NEWEMB  = 75497474;
constexpr size_t O_CLUSTER = 75530242;
constexpr size_t O_NEWEMAW = 75530754;

// workspace float offsets (total = 34,351,104 B — proven to fit in round 3)
constexpr size_t F_IDX   = 0;         // 131072 ints
constexpr size_t F_LOSS  = 131072;    // 1 float
constexpr size_t F_SE32  = 131584;    // 512 floats; reused as start[512] ints after argmin
constexpr size_t F_SE64  = 132096;    // 512 doubles
constexpr size_t F_EHI   = 133120;    // 512x64 ushort; reused as parts[64][512] ints after argmin
constexpr size_t F_ELO   = 149504;    // 512x64 ushort (second half of parts region)
constexpr size_t F_CNT   = 165888;    // 512 floats
constexpr size_t F_DW    = 166400;    // 32768 floats
constexpr size_t F_AUX   = 199168;    // flat (token-major x) OR partials
constexpr int    kPartStride = 33280; // 32768 dw + 512 hist (fallback)

constexpr float kMargin = 0.01f;      // computed-gap below which we fp64-rescan

typedef __attribute__((ext_vector_type(8))) short short8;
typedef __attribute__((ext_vector_type(4))) float f32x4;
typedef __attribute__((ext_vector_type(2))) float f32x2;
typedef __attribute__((ext_vector_type(4))) unsigned short us4;
}

__device__ __forceinline__ unsigned short f2bf(float f) {
  unsigned u = __builtin_bit_cast(unsigned, f);
  unsigned r = (u + 0x7FFFu + ((u >> 16) & 1u)) >> 16;
  return (unsigned short)r;
}
__device__ __forceinline__ float bf2f(unsigned short h) {
  unsigned u = (unsigned)h << 16;
  return __builtin_bit_cast(float, u);
}

// ||e||^2 (fp64 + fp32) and bf16 hi/lo split of the codebook.
extern "C" __global__ void vq_se2(const float* __restrict__ emb,
                                  float* __restrict__ se32,
                                  double* __restrict__ se64,
                                  unsigned short* __restrict__ ehi,
                                  unsigned short* __restrict__ elo) {
  int j = blockIdx.x * blockDim.x + threadIdx.x;
  if (j >= kNE) return;
  const float4* e4 = (const float4*)(emb + (size_t)j * kED);
  double s = 0.0;
  for (int i = 0; i < 16; ++i) {
    float4 v = e4[i];
    s += (double)v.x * v.x + (double)v.y * v.y
       + (double)v.z * v.z + (double)v.w * v.w;
    us4 h, l;
    float f[4] = {v.x, v.y, v.z, v.w};
    unsigned short hh[4], ll[4];
    #pragma unroll
    for (int t = 0; t < 4; ++t) {
      hh[t] = f2bf(f[t]);
      ll[t] = f2bf(f[t] - bf2f(hh[t]));
    }
    h.x = hh[0]; h.y = hh[1]; h.z = hh[2]; h.w = hh[3];
    l.x = ll[0]; l.y = ll[1]; l.z = ll[2]; l.w = ll[3];
    *(us4*)&ehi[(size_t)j * kED + i * 4] = h;
    *(us4*)&elo[(size_t)j * kED + i * 4] = l;
  }
  se64[j] = s;
  se32[j] = (float)s;
}

// MFMA argmin: idx + token-major flat only (streaming outputs moved out).
extern "C" __global__ __launch_bounds__(kThreads) void vq_argmin(
    const float* __restrict__ x, const float* __restrict__ emb,
    const float* __restrict__ se32, const double* __restrict__ se64,
    const unsigned short* __restrict__ ehi, const unsigned short* __restrict__ elo,
    int* __restrict__ idx_out, float* __restrict__ flat_ws, int write_flat) {
  __shared__ float flat[kTokPerBlk][65];                      // fp32 token tile
  __shared__ __attribute__((aligned(16))) unsigned short ahi[kTokPerBlk][72];
  __shared__ __attribute__((aligned(16))) unsigned short alo[kTokPerBlk][72];
  __shared__ __attribute__((aligned(16))) unsigned short bhi[128][72];
  __shared__ __attribute__((aligned(16))) unsigned short blo[128][72];
  __shared__ float se_lds[kNE];
  __shared__ float tok_best[kTokPerBlk];
  __shared__ float tok_sec[kTokPerBlk];
  __shared__ int   tok_idx[kTokPerBlk];
  __shared__ int   flag_list[kTokPerBlk];
  __shared__ int   flag_cnt;
  __shared__ double redd[kThreads];
  __shared__ int    redj[kThreads];

  const int tid = threadIdx.x;
  const int token_base = blockIdx.x * kTokPerBlk;
  const int batch = token_base / kHW;
  const int pos0  = token_base % kHW;     // tiles never cross batch

  if (tid == 0) flag_cnt = 0;

  // ---- stage x tile (transpose NCHW -> token-major, fp32) ----
  const float* xb = x + (size_t)batch * kED * kHW + pos0;
  {
    const int p  = tid & 63;
    const int d0 = tid >> 6;
    #pragma unroll
    for (int i = 0; i < 16; ++i) {
      int d = i * 4 + d0;
      flat[p][d] = xb[(size_t)d * kHW + p];
    }
  }
  se_lds[tid] = se32[tid];
  se_lds[tid + 256] = se32[tid + 256];
  __syncthreads();

  // ---- bf16 hi/lo split of the token tile ----
  {
    const int r  = tid >> 2;
    const int d0 = (tid & 3) * 16;
    #pragma unroll
    for (int i = 0; i < 8; ++i) {
      int d = d0 + i * 2;
      float v0 = flat[r][d], v1 = flat[r][d + 1];
      unsigned short h0 = f2bf(v0), h1 = f2bf(v1);
      unsigned short l0 = f2bf(v0 - bf2f(h0)), l1 = f2bf(v1 - bf2f(h1));
      *(unsigned*)&ahi[r][d] = (unsigned)h0 | ((unsigned)h1 << 16);
      *(unsigned*)&alo[r][d] = (unsigned)l0 | ((unsigned)l1 << 16);
    }
  }
  __syncthreads();

  // ---- per-wave A fragments (persist across all chunks) ----
  const int lane = tid & 63;
  const int wv   = tid >> 6;
  const int qd   = lane >> 4;
  const int ml   = lane & 15;
  const int arow = wv * 16 + ml;
  const char* abase_h = (const char*)&ahi[0][0] + arow * 144 + qd * 16;
  const char* abase_l = (const char*)&alo[0][0] + arow * 144 + qd * 16;
  short8 a_h0 = *(const short8*)(abase_h);
  short8 a_h1 = *(const short8*)(abase_h + 64);
  short8 a_l0 = *(const short8*)(abase_l);
  short8 a_l1 = *(const short8*)(abase_l + 64);

  float bestv[4], secv[4];
  int   bestj[4];
  #pragma unroll
  for (int r = 0; r < 4; ++r) { bestv[r] = INFINITY; secv[r] = INFINITY; bestj[r] = 0; }

  // ---- 4 chunks of 128 codes: bf16x3 MFMA distances (lo*lo dropped) ----
  for (int c0 = 0; c0 < kNE; c0 += 128) {
    __syncthreads();
    {
      const char* srch = (const char*)ehi + (size_t)c0 * 128;
      const char* srcl = (const char*)elo + (size_t)c0 * 128;
      #pragma unroll
      for (int i = 0; i < 4; ++i) {
        int q = i * kThreads + tid;     // 0..1023 (128 rows x 8 segs)
        int row = q >> 3, seg = q & 7;
        *(float4*)((char*)&bhi[0][0] + row * 144 + seg * 16) =
            *(const float4*)(srch + row * 128 + seg * 16);
        *(float4*)((char*)&blo[0][0] + row * 144 + seg * 16) =
            *(const float4*)(srcl + row * 128 + seg * 16);
      }
    }
    __syncthreads();

    for (int nt = 0; nt < 8; nt += 2) {
      const int cc0 = nt * 16 + ml;
      const int cc1 = cc0 + 16;
      const char* b0h = (const char*)&bhi[0][0] + cc0 * 144 + qd * 16;
      const char* b0l = (const char*)&blo[0][0] + cc0 * 144 + qd * 16;
      const char* b1h = (const char*)&bhi[0][0] + cc1 * 144 + qd * 16;
      const char* b1l = (const char*)&blo[0][0] + cc1 * 144 + qd * 16;
      short8 bh00 = *(const short8*)(b0h);
      short8 bh01 = *(const short8*)(b0h + 64);
      short8 bl00 = *(const short8*)(b0l);
      short8 bl01 = *(const short8*)(b0l + 64);
      short8 bh10 = *(const short8*)(b1h);
      short8 bh11 = *(const short8*)(b1h + 64);
      short8 bl10 = *(const short8*)(b1l);
      short8 bl11 = *(const short8*)(b1l + 64);

      f32x4 acc0 = {0.f, 0.f, 0.f, 0.f};
      f32x4 acc1 = {0.f, 0.f, 0.f, 0.f};
      acc0 = __builtin_amdgcn_mfma_f32_16x16x32_bf16(a_h0, bh00, acc0, 0, 0, 0);
      acc1 = __builtin_amdgcn_mfma_f32_16x16x32_bf16(a_h0, bh10, acc1, 0, 0, 0);
      acc0 = __builtin_amdgcn_mfma_f32_16x16x32_bf16(a_h1, bh01, acc0, 0, 0, 0);
      acc1 = __builtin_amdgcn_mfma_f32_16x16x32_bf16(a_h1, bh11, acc1, 0, 0, 0);
      acc0 = __builtin_amdgcn_mfma_f32_16x16x32_bf16(a_l0, bh00, acc0, 0, 0, 0);
      acc1 = __builtin_amdgcn_mfma_f32_16x16x32_bf16(a_l0, bh10, acc1, 0, 0, 0);
      acc0 = __builtin_amdgcn_mfma_f32_16x16x32_bf16(a_l1, bh01, acc0, 0, 0, 0);
      acc1 = __builtin_amdgcn_mfma_f32_16x16x32_bf16(a_l1, bh11, acc1, 0, 0, 0);
      acc0 = __builtin_amdgcn_mfma_f32_16x16x32_bf16(a_h0, bl00, acc0, 0, 0, 0);
      acc1 = __builtin_amdgcn_mfma_f32_16x16x32_bf16(a_h0, bl10, acc1, 0, 0, 0);
      acc0 = __builtin_amdgcn_mfma_f32_16x16x32_bf16(a_h1, bl01, acc0, 0, 0, 0);
      acc1 = __builtin_amdgcn_mfma_f32_16x16x32_bf16(a_h1, bl11, acc1, 0, 0, 0);

      const int j0 = c0 + nt * 16 + ml;
      const int j1 = j0 + 16;
      const float s0 = se_lds[j0];
      const float s1 = se_lds[j1];
      #pragma unroll
      for (int r = 0; r < 4; ++r) {
        float v0 = s0 - 2.f * acc0[r];
        if (v0 < bestv[r]) { secv[r] = bestv[r]; bestv[r] = v0; bestj[r] = j0; }
        else secv[r] = fminf(secv[r], v0);
        float v1 = s1 - 2.f * acc1[r];
        if (v1 < bestv[r]) { secv[r] = bestv[r]; bestv[r] = v1; bestj[r] = j1; }
        else secv[r] = fminf(secv[r], v1);
      }
    }
  }

  // ---- cross-lane merge within each 16-lane quad group ----
  #pragma unroll
  for (int off = 1; off < 16; off <<= 1) {
    #pragma unroll
    for (int r = 0; r < 4; ++r) {
      float ov = __shfl_xor(bestv[r], off, 16);
      float os = __shfl_xor(secv[r], off, 16);
      int   oj = __shfl_xor(bestj[r], off, 16);
      bool take = (ov < bestv[r]) || (ov == bestv[r] && oj < bestj[r]);
      float loser = take ? bestv[r] : ov;
      bestv[r] = take ? ov : bestv[r];
      bestj[r] = take ? oj : bestj[r];
      secv[r]  = fminf(fminf(loser, os), secv[r]);
    }
  }
  if (ml == 0) {
    #pragma unroll
    for (int r = 0; r < 4; ++r) {
      int m = wv * 16 + qd * 4 + r;
      tok_best[m] = bestv[r];
      tok_sec[m]  = secv[r];
      tok_idx[m]  = bestj[r];
    }
  }
  __syncthreads();

  if (tid < kTokPerBlk) {
    if (tok_sec[tid] - tok_best[tid] < kMargin) {
      int p = atomicAdd(&flag_cnt, 1);
      flag_list[p] = tid;
    }
  }
  __syncthreads();

  const int nflag = flag_cnt;
  for (int fi = 0; fi < nflag; ++fi) {
    const int tr = flag_list[fi];
    double db = 1e300; int dbj = 0;
    #pragma unroll 1
    for (int jj = 0; jj < 2; ++jj) {
      int j = tid * 2 + jj;
      const float* er = emb + (size_t)j * kED;
      double a0 = 0.0, a1 = 0.0, a2 = 0.0, a3 = 0.0;
      #pragma unroll
      for (int d = 0; d < kED; d += 4) {
        a0 = __builtin_fma((double)flat[tr][d+0], (double)er[d+0], a0);
        a1 = __builtin_fma((double)flat[tr][d+1], (double)er[d+1], a1);
        a2 = __builtin_fma((double)flat[tr][d+2], (double)er[d+2], a2);
        a3 = __builtin_fma((double)flat[tr][d+3], (double)er[d+3], a3);
      }
      double dist = se64[j] - 2.0 * ((a0 + a1) + (a2 + a3));
      if (dist < db || (dist == db && j < dbj)) { db = dist; dbj = j; }
    }
    redd[tid] = db; redj[tid] = dbj;
    __syncthreads();
    for (int s2 = kThreads / 2; s2 > 0; s2 >>= 1) {
      if (tid < s2) {
        double v = redd[tid + s2]; int j = redj[tid + s2];
        if (v < redd[tid] || (v == redd[tid] && j < redj[tid])) {
          redd[tid] = v; redj[tid] = j;
        }
      }
      __syncthreads();
    }
    if (tid == 0) tok_idx[tr] = redj[0];
    __syncthreads();
  }

  if (tid < kTokPerBlk) idx_out[token_base + tid] = tok_idx[tid];
  if (write_flat) {
    const int r  = tid >> 2;
    const int d0 = (tid & 3) * 16;
    float* dst = flat_ws + (size_t)(token_base + r) * kED + d0;
    #pragma unroll
    for (int i = 0; i < 4; ++i) {
      f32x4 v = {flat[r][d0 + i*4], flat[r][d0 + i*4 + 1],
                 flat[r][d0 + i*4 + 2], flat[r][d0 + i*4 + 3]};
      *(f32x4*)(dst + i * 4) = v;
    }
  }
}

// ---- counting sort for dw: hist -> scan -> scatter -> gather ----
extern "C" __global__ __launch_bounds__(kThreads) void vq_hist(
    const int* __restrict__ idx, int* __restrict__ parts) {
  __shared__ int h[kNE];
  const int tid = threadIdx.x, b = blockIdx.x;
  h[tid] = 0; h[tid + 256] = 0;
  __syncthreads();
  #pragma unroll
  for (int it = 0; it < 8; ++it)
    atomicAdd(&h[idx[b * 2048 + it * 256 + tid]], 1);
  __syncthreads();
  parts[b * kNE + tid] = h[tid];
  parts[b * kNE + tid + 256] = h[tid + 256];
}

extern "C" __global__ __launch_bounds__(512) void vq_scan(
    int* __restrict__ parts, int* __restrict__ start,
    float* __restrict__ cnt) {
  __shared__ int pl[64 * kNE];   // 128 KB
  __shared__ int sh[kNE];
  const int c = threadIdx.x;     // 0..511
  for (int i = c; i < 64 * kNE; i += 512) pl[i] = parts[i];
  __syncthreads();
  int run = 0;
  #pragma unroll 1
  for (int p = 0; p < 64; ++p) {
    int t = pl[p * kNE + c];
    pl[p * kNE + c] = run;
    run += t;
  }
  sh[c] = run;
  cnt[c] = (float)run;
  __syncthreads();
  #pragma unroll 1
  for (int off = 1; off < kNE; off <<= 1) {
    int t = (c >= off) ? sh[c - off] : 0;
    __syncthreads();
    sh[c] += t;
    __syncthreads();
  }
  int st = sh[c] - run;
  start[c] = st;
  #pragma unroll 1
  for (int p = 0; p < 64; ++p)
    parts[p * kNE + c] = st + pl[p * kNE + c];
}

extern "C" __global__ __launch_bounds__(kThreads) void vq_scatter(
    const int* __restrict__ idx, const int* __restrict__ parts,
    int* __restrict__ sorted) {
  __shared__ int cur[kNE];
  const int tid = threadIdx.x, b = blockIdx.x;
  cur[tid] = parts[b * kNE + tid];
  cur[tid + 256] = parts[b * kNE + tid + 256];
  __syncthreads();
  #pragma unroll
  for (int it = 0; it < 8; ++it) {
    int i = b * 2048 + it * 256 + tid;
    int c = idx[i];
    int pos = atomicAdd(&cur[c], 1);
    sorted[pos] = i;
  }
}

extern "C" __global__ __launch_bounds__(kThreads) void vq_gather(
    const float* __restrict__ flat, const int* __restrict__ sorted,
    const int* __restrict__ start, float* __restrict__ dwf) {
  __shared__ float accs[4 * kED];
  const int tid = threadIdx.x, c = blockIdx.x;
  const int s = start[c];
  const int n = ((c == kNE - 1) ? kNTok : start[c + 1]) - s;
  const int tt = tid >> 6, d = tid & 63;
  float a = 0.f;
  for (int it = tt; it < n; it += 4)
    a += flat[(size_t)sorted[s + it] * kED + d];
  accs[tt * kED + d] = a;
  __syncthreads();
  if (tid < kED)
    dwf[(size_t)c * kED + d] =
        (accs[d] + accs[kED + d]) + (accs[2 * kED + d] + accs[3 * kED + d]);
}

// ---- streaming outputs ----
extern "C" __global__ __launch_bounds__(kThreads) void vq_enc(
    const int* __restrict__ idx, float* __restrict__ enc) {
  __shared__ int ti[kTokPerBlk];
  const int tid = threadIdx.x;
  const int token_base = blockIdx.x * kTokPerBlk;
  if (tid < kTokPerBlk) ti[tid] = idx[token_base + tid];
  __syncthreads();
  f32x2* encb2 = (f32x2*)(enc + (size_t)token_base * kNE);
  #pragma unroll 4
  for (int i = 0; i < 64; ++i) {
    int q = i * kThreads + tid;   // float2 idx, 0..16383
    int row = q >> 8;
    int c2  = (q & 255) * 2;
    int bi = ti[row];
    f32x2 v;
    v.x = (bi == c2)     ? 1.f : 0.f;
    v.y = (bi == c2 + 1) ? 1.f : 0.f;
    __builtin_nontemporal_store(v, &encb2[q]);
  }
}

extern "C" __global__ __launch_bounds__(kThreads) void vq_out(
    const float* __restrict__ x, const float* __restrict__ emb,
    const int* __restrict__ idx, float* __restrict__ out_q,
    float* __restrict__ loss_sum) {
  __shared__ float qt[kTokPerBlk * 65];
  __shared__ int ti[kTokPerBlk];
  __shared__ float lred[4];
  const int tid = threadIdx.x;
  const int token_base = blockIdx.x * kTokPerBlk;
  const int batch = token_base / kHW;
  const int pos0  = token_base % kHW;
  if (tid < kTokPerBlk) ti[tid] = idx[token_base + tid];
  __syncthreads();
  {
    int rr = tid >> 2;
    int c0 = (tid & 3) * 16;
    const float* er = emb + (size_t)ti[rr] * kED;
    #pragma unroll
    for (int i = 0; i < 4; ++i) {
      float4 v = *(const float4*)(er + c0 + i * 4);
      qt[rr * 65 + c0 + i * 4 + 0] = v.x;
      qt[rr * 65 + c0 + i * 4 + 1] = v.y;
      qt[rr * 65 + c0 + i * 4 + 2] = v.z;
      qt[rr * 65 + c0 + i * 4 + 3] = v.w;
    }
  }
  __syncthreads();
  float lacc = 0.f;
  {
    const float* xb = x + (size_t)batch * kED * kHW + pos0;
    float* outb = out_q + (size_t)batch * kED * kHW + pos0;
    const int p  = tid & 63;
    const int c0 = tid >> 6;
    #pragma unroll
    for (int i = 0; i < 16; ++i) {
      int c = i * 4 + c0;
      float inv  = xb[(size_t)c * kHW + p];
      float qv   = qt[p * 65 + c];
      float diff = qv - inv;
      __builtin_nontemporal_store(inv + diff, &outb[(size_t)c * kHW + p]);
      lacc = __builtin_fmaf(diff, diff, lacc);
    }
  }
  #pragma unroll
  for (int off = 32; off > 0; off >>= 1) lacc += __shfl_down(lacc, off, 64);
  if ((tid & 63) == 0) lred[tid >> 6] = lacc;
  __syncthreads();
  if (tid == 0)
    atomicAdd(loss_sum, (lred[0] + lred[1]) + (lred[2] + lred[3]));
}

// ---- fallback path (small ws): per-block LDS partials + dense reduce ----
extern "C" __global__ __launch_bounds__(kThreads) void vq_dw_part(
    const float* __restrict__ x, const int* __restrict__ idx,
    float* __restrict__ part, int G) {
  __shared__ float dwacc[kNE * kED];
  __shared__ int   hist[kNE];
  __shared__ float flat[kTokPerBlk][65];
  __shared__ int   idxs[kTokPerBlk];
  const int tid = threadIdx.x;
  #pragma unroll
  for (int i = 0; i < kNE * kED / kThreads; ++i) dwacc[i * kThreads + tid] = 0.f;
  for (int i = tid; i < kNE; i += kThreads) hist[i] = 0;
  __syncthreads();
  for (int tile = blockIdx.x; tile < kNTiles; tile += G) {
    const int token_base = tile * kTokPerBlk;
    const int batch = token_base / kHW;
    const int pos0  = token_base % kHW;
    const float* xb = x + (size_t)batch * kED * kHW + pos0;
    {
      const int p  = tid & 63;
      const int d0 = tid >> 6;
      #pragma unroll
      for (int i = 0; i < 16; ++i) {
        int d = i * 4 + d0;
        flat[p][d] = xb[(size_t)d * kHW + p];
      }
    }
    if (tid < kTokPerBlk) idxs[tid] = idx[token_base + tid];
    __syncthreads();
    {
      const int w = tid >> 6;
      const int d = tid & 63;
      #pragma unroll
      for (int i = 0; i < 16; ++i) {
        int rr = w + i * 4;
        atomicAdd(&dwacc[idxs[rr] * kED + d], flat[rr][d]);
      }
    }
    if (tid < kTokPerBlk) atomicAdd(&hist[idxs[tid]], 1);
    __syncthreads();
  }
  float* dst = part + (size_t)blockIdx.x * kPartStride;
  #pragma unroll
  for (int i = 0; i < kNE * kED / kThreads / 4; ++i) {
    int q = i * kThreads + tid;
    *(float4*)&dst[q * 4] = *(float4*)&dwacc[q * 4];
  }
  #pragma unroll
  for (int i = 0; i < kNE / kThreads; ++i) {
    int q = i * kThreads + tid;
    dst[kNE * kED + q] = (float)hist[q];
  }
}

extern "C" __global__ void vq_red(const float* __restrict__ part,
                                  float* __restrict__ dwf,
                                  float* __restrict__ cnt, int G) {
  int i = blockIdx.x * blockDim.x + threadIdx.x;
  if (i >= kPartStride) return;
  float s0 = 0.f, s1 = 0.f, s2 = 0.f, s3 = 0.f;
  int p = 0;
  for (; p + 3 < G; p += 4) {
    s0 += part[(size_t)(p + 0) * kPartStride + i];
    s1 += part[(size_t)(p + 1) * kPartStride + i];
    s2 += part[(size_t)(p + 2) * kPartStride + i];
    s3 += part[(size_t)(p + 3) * kPartStride + i];
  }
  for (; p < G; ++p) s0 += part[(size_t)p * kPartStride + i];
  float s = (s0 + s1) + (s2 + s3);
  if (i < kNE * kED) dwf[i] = s;
  else cnt[i - kNE * kED] = s;
}

extern "C" __global__ __launch_bounds__(kThreads) void vq_dw_atomic(
    const float* __restrict__ x, const int* __restrict__ idx,
    float* __restrict__ dwf, float* __restrict__ cnt) {
  __shared__ float flat[kTokPerBlk][65];
  __shared__ int   idxs[kTokPerBlk];
  const int tid = threadIdx.x;
  const int token_base = blockIdx.x * kTokPerBlk;
  const int batch = token_base / kHW;
  const int pos0  = token_base % kHW;
  const float* xb = x + (size_t)batch * kED * kHW + pos0;
  {
    const int p  = tid & 63;
    const int d0 = tid >> 6;
    #pragma unroll
    for (int i = 0; i < 16; ++i) {
      int d = i * 4 + d0;
      flat[p][d] = xb[(size_t)d * kHW + p];
    }
  }
  if (tid < kTokPerBlk) idxs[tid] = idx[token_base + tid];
  __syncthreads();
  {
    int rr = tid >> 2;
    int c0 = (tid & 3) * 16;
    float* dwr = dwf + (size_t)idxs[rr] * kED;
    #pragma unroll
    for (int i = 0; i < 16; ++i) atomicAdd(&dwr[c0 + i], flat[rr][c0 + i]);
  }
  if (tid < kTokPerBlk) atomicAdd(&cnt[idxs[tid]], 1.0f);
}

// cluster Laplace smoothing, perplexity, loss
extern "C" __global__ void vq_fin_a(const float* __restrict__ ema_cs,
                                    const float* __restrict__ counts,
                                    const float* __restrict__ loss_sum,
                                    float* __restrict__ out) {
  __shared__ float red[kNE];
  const int j = threadIdx.x;
  float craw = ema_cs[j] * 0.99f + 0.01f * counts[j];
  red[j] = craw;
  __syncthreads();
  for (int s = kNE / 2; s > 0; s >>= 1) {
    if (j < s) red[j] += red[j + s];
    __syncthreads();
  }
  float k = red[0];
  __syncthreads();
  float clu = (craw + 1e-5f) / (k + kNE * 1e-5f) * k;
  out[O_CLUSTER + j] = clu;
  float avg = counts[j] * (1.0f / 131072.0f);
  float term = avg * logf(avg + 1e-10f);
  red[j] = term;
  __syncthreads();
  for (int s = kNE / 2; s > 0; s >>= 1) {
    if (j < s) red[j] += red[j + s];
    __syncthreads();
  }
  if (j == 0) {
    out[O_PERP] = expf(-red[0]);
    out[O_LOSS] = 0.25f * loss_sum[0] * (1.0f / 8388608.0f);
  }
}

extern "C" __global__ void vq_fin_b(const float* __restrict__ ema_w,
                                    const float* __restrict__ dw,
                                    const float* __restrict__ out_cluster,
                                    float* __restrict__ out) {
  int i = blockIdx.x * blockDim.x + threadIdx.x;   // 0..32767
  int j = i >> 6;
  float nw = ema_w[i] * 0.99f + 0.01f * dw[i];
  out[O_NEWEMAW + i] = nw;
  out[O_NEWEMB + i] = nw / out_cluster[j];
}

extern "C" void kernel_launch(void* const* d_in, const int* in_sizes, int n_in,
                              void* d_out, int out_size, void* d_ws, size_t ws_size,
                              hipStream_t stream) {
  const float* x      = (const float*)d_in[0];
  const float* emb    = (const float*)d_in[1];
  const float* ema_w  = (const float*)d_in[2];
  const float* ema_cs = (const float*)d_in[3];
  float* out = (float*)d_out;
  float* ws  = (float*)d_ws;

  int*    idxb     = (int*)d_ws;
  float*  loss_sum = ws + F_LOSS;
  float*  se32     = ws + F_SE32;
  double* se64     = (double*)(ws + F_SE64);
  unsigned short* ehi = (unsigned short*)(ws + F_EHI);
  unsigned short* elo = (unsigned short*)(ws + F_ELO);
  float*  cnt      = ws + F_CNT;
  float*  dwf      = ws + F_DW;
  float*  aux      = ws + F_AUX;          // flat (token-major x) OR partials
  int*    parts    = (int*)(ws + F_EHI);  // reuse ehi+elo after argmin
  int*    startp   = (int*)(ws + F_SE32); // reuse se32 after argmin
  int*    sorted   = (int*)(out + O_ENC); // enc region scratch, overwritten by vq_enc

  const size_t need_flat = (F_AUX + (size_t)kNTok * kED) * 4;
  const bool flat_ok = ws_size >= need_flat;
  int G = 0;
  if (!flat_ok) {
    long avail = (long)(ws_size / 4) - (long)F_AUX;
    G = avail > 0 ? (int)(avail / kPartStride) : 0;
    if (G > 256) G = 256;
  }
  const bool part_ok = (G >= 8);

  hipMemsetAsync(ws + F_LOSS, 0, sizeof(float), stream);
  if (!flat_ok && !part_ok)
    hipMemsetAsync(ws + F_CNT, 0, (kNE + kNE * kED) * sizeof(float), stream);

  hipLaunchKernelGGL(vq_se2, dim3(2), dim3(256), 0, stream,
                     emb, se32, se64, ehi, elo);
  hipLaunchKernelGGL(vq_argmin, dim3(kNTiles), dim3(kThreads), 0, stream,
                     x, emb, se32, se64, ehi, elo, idxb, aux, flat_ok ? 1 : 0);
  if (flat_ok) {
    hipLaunchKernelGGL(vq_hist, dim3(64), dim3(kThreads), 0, stream,
                       idxb, parts);
    hipLaunchKernelGGL(vq_scan, dim3(1), dim3(512), 0, stream,
                       parts, startp, cnt);
    hipLaunchKernelGGL(vq_scatter, dim3(64), dim3(kThreads), 0, stream,
                       idxb, parts, sorted);
    hipLaunchKernelGGL(vq_gather, dim3(kNE), dim3(kThreads), 0, stream,
                       aux, sorted, startp, dwf);
  } else if (part_ok) {
    hipLaunchKernelGGL(vq_dw_part, dim3(G), dim3(kThreads), 0, stream,
                       x, idxb, aux, G);
    hipLaunchKernelGGL(vq_red, dim3((kPartStride + 255) / 256), dim3(256), 0,
                       stream, aux, dwf, cnt, G);
  } else {
    hipLaunchKernelGGL(vq_dw_atomic, dim3(kNTiles), dim3(kThreads), 0, stream,
                       x, idxb, dwf, cnt);
  }
  hipLaunchKernelGGL(vq_enc, dim3(kNTiles), dim3(kThreads), 0, stream,
                     idxb, out + O_ENC);
  hipLaunchKernelGGL(vq_out, dim3(kNTiles), dim3(kThreads), 0, stream,
                     x, emb, idxb, out + O_OUT, loss_sum);
  hipLaunchKernelGGL(vq_fin_a, dim3(1), dim3(kNE), 0, stream,
                     ema_cs, cnt, loss_sum, out);
  hipLaunchKernelGGL(vq_fin_b, dim3(kNE * kED / 256), dim3(256), 0, stream,
                     ema_w, dwf, out + O_CLUSTER, out);
}

// Round 5
// 532.874 us; speedup vs baseline: 1.8028x; 1.8028x over previous
//
#include <hip/hip_runtime.h>
#include <math.h>

namespace {
constexpr int kNE = 512;          // num codebook entries
constexpr int kED = 64;           // embed dim
constexpr int kHW = 4096;         // 64*64 spatial
constexpr int kNTiles = 2048;     // 64-token tiles
constexpr int kNTok = 131072;
constexpr int kTokPerBlk = 64;
constexpr int kThreads = 256;

// output float offsets (return order: loss, out, perplexity, encodings,
// new_embedding, cluster, new_ema_w)
constexpr size_t O_LOSS    = 0;
constexpr size_t O_OUT     = 1;
constexpr size_t O_PERP    = 8388609;
constexpr size_t O_ENC     = 8388610;   // byte-align 8 (float2 ok, float4 NOT)
constexpr size_t O_NEWEMB  = 75497474;
constexpr size_t O_CLUSTER = 75530242;
constexpr size_t O_NEWEMAW = 75530754;

// workspace float offsets (total = 34,351,104 B — proven to fit)
constexpr size_t F_IDX   = 0;         // 131072 ints
constexpr size_t F_LOSS  = 131072;    // 1 float
constexpr size_t F_SE32  = 131584;    // 512 floats; reused as start[512] ints after argmin
constexpr size_t F_SE64  = 132096;    // 512 doubles
constexpr size_t F_EHI   = 133120;    // 512x64 ushort; reused as parts[64][512] ints after argmin
constexpr size_t F_ELO   = 149504;    // 512x64 ushort (second half of parts region)
constexpr size_t F_CNT   = 165888;    // 512 floats
constexpr size_t F_DW    = 166400;    // 32768 floats
constexpr size_t F_AUX   = 199168;    // flat (token-major x) OR partials
constexpr int    kPartStride = 33280; // 32768 dw + 512 hist (fallback)

constexpr float kMargin = 0.01f;      // computed-gap below which we fp64-rescan

typedef __attribute__((ext_vector_type(8))) short short8;
typedef __attribute__((ext_vector_type(4))) float f32x4;
typedef __attribute__((ext_vector_type(2))) float f32x2;
typedef __attribute__((ext_vector_type(4))) unsigned short us4;
}

__device__ __forceinline__ unsigned short f2bf(float f) {
  unsigned u = __builtin_bit_cast(unsigned, f);
  unsigned r = (u + 0x7FFFu + ((u >> 16) & 1u)) >> 16;
  return (unsigned short)r;
}
__device__ __forceinline__ float bf2f(unsigned short h) {
  unsigned u = (unsigned)h << 16;
  return __builtin_bit_cast(float, u);
}

// ||e||^2 (fp64 + fp32) and bf16 hi/lo split of the codebook.
extern "C" __global__ void vq_se2(const float* __restrict__ emb,
                                  float* __restrict__ se32,
                                  double* __restrict__ se64,
                                  unsigned short* __restrict__ ehi,
                                  unsigned short* __restrict__ elo) {
  int j = blockIdx.x * blockDim.x + threadIdx.x;
  if (j >= kNE) return;
  const float4* e4 = (const float4*)(emb + (size_t)j * kED);
  double s = 0.0;
  for (int i = 0; i < 16; ++i) {
    float4 v = e4[i];
    s += (double)v.x * v.x + (double)v.y * v.y
       + (double)v.z * v.z + (double)v.w * v.w;
    us4 h, l;
    float f[4] = {v.x, v.y, v.z, v.w};
    unsigned short hh[4], ll[4];
    #pragma unroll
    for (int t = 0; t < 4; ++t) {
      hh[t] = f2bf(f[t]);
      ll[t] = f2bf(f[t] - bf2f(hh[t]));
    }
    h.x = hh[0]; h.y = hh[1]; h.z = hh[2]; h.w = hh[3];
    l.x = ll[0]; l.y = ll[1]; l.z = ll[2]; l.w = ll[3];
    *(us4*)&ehi[(size_t)j * kED + i * 4] = h;
    *(us4*)&elo[(size_t)j * kED + i * 4] = l;
  }
  se64[j] = s;
  se32[j] = (float)s;
}

// MFMA argmin: idx + token-major flat only.
extern "C" __global__ __launch_bounds__(kThreads) void vq_argmin(
    const float* __restrict__ x, const float* __restrict__ emb,
    const float* __restrict__ se32, const double* __restrict__ se64,
    const unsigned short* __restrict__ ehi, const unsigned short* __restrict__ elo,
    int* __restrict__ idx_out, float* __restrict__ flat_ws, int write_flat) {
  __shared__ float flat[kTokPerBlk][65];                      // fp32 token tile
  __shared__ __attribute__((aligned(16))) unsigned short ahi[kTokPerBlk][72];
  __shared__ __attribute__((aligned(16))) unsigned short alo[kTokPerBlk][72];
  __shared__ __attribute__((aligned(16))) unsigned short bhi[128][72];
  __shared__ __attribute__((aligned(16))) unsigned short blo[128][72];
  __shared__ float se_lds[kNE];
  __shared__ float tok_best[kTokPerBlk];
  __shared__ float tok_sec[kTokPerBlk];
  __shared__ int   tok_idx[kTokPerBlk];
  __shared__ int   flag_list[kTokPerBlk];
  __shared__ int   flag_cnt;
  __shared__ double redd[kThreads];
  __shared__ int    redj[kThreads];

  const int tid = threadIdx.x;
  const int token_base = blockIdx.x * kTokPerBlk;
  const int batch = token_base / kHW;
  const int pos0  = token_base % kHW;     // tiles never cross batch

  if (tid == 0) flag_cnt = 0;

  // ---- stage x tile (transpose NCHW -> token-major, fp32) ----
  const float* xb = x + (size_t)batch * kED * kHW + pos0;
  {
    const int p  = tid & 63;
    const int d0 = tid >> 6;
    #pragma unroll
    for (int i = 0; i < 16; ++i) {
      int d = i * 4 + d0;
      flat[p][d] = xb[(size_t)d * kHW + p];
    }
  }
  se_lds[tid] = se32[tid];
  se_lds[tid + 256] = se32[tid + 256];
  __syncthreads();

  // ---- bf16 hi/lo split of the token tile ----
  {
    const int r  = tid >> 2;
    const int d0 = (tid & 3) * 16;
    #pragma unroll
    for (int i = 0; i < 8; ++i) {
      int d = d0 + i * 2;
      float v0 = flat[r][d], v1 = flat[r][d + 1];
      unsigned short h0 = f2bf(v0), h1 = f2bf(v1);
      unsigned short l0 = f2bf(v0 - bf2f(h0)), l1 = f2bf(v1 - bf2f(h1));
      *(unsigned*)&ahi[r][d] = (unsigned)h0 | ((unsigned)h1 << 16);
      *(unsigned*)&alo[r][d] = (unsigned)l0 | ((unsigned)l1 << 16);
    }
  }
  __syncthreads();

  // ---- per-wave A fragments (persist across all chunks) ----
  const int lane = tid & 63;
  const int wv   = tid >> 6;
  const int qd   = lane >> 4;
  const int ml   = lane & 15;
  const int arow = wv * 16 + ml;
  const char* abase_h = (const char*)&ahi[0][0] + arow * 144 + qd * 16;
  const char* abase_l = (const char*)&alo[0][0] + arow * 144 + qd * 16;
  short8 a_h0 = *(const short8*)(abase_h);
  short8 a_h1 = *(const short8*)(abase_h + 64);
  short8 a_l0 = *(const short8*)(abase_l);
  short8 a_l1 = *(const short8*)(abase_l + 64);

  float bestv[4], secv[4];
  int   bestj[4];
  #pragma unroll
  for (int r = 0; r < 4; ++r) { bestv[r] = INFINITY; secv[r] = INFINITY; bestj[r] = 0; }

  // ---- 4 chunks of 128 codes: bf16x3 MFMA distances (lo*lo dropped) ----
  for (int c0 = 0; c0 < kNE; c0 += 128) {
    __syncthreads();
    {
      const char* srch = (const char*)ehi + (size_t)c0 * 128;
      const char* srcl = (const char*)elo + (size_t)c0 * 128;
      #pragma unroll
      for (int i = 0; i < 4; ++i) {
        int q = i * kThreads + tid;     // 0..1023 (128 rows x 8 segs)
        int row = q >> 3, seg = q & 7;
        *(float4*)((char*)&bhi[0][0] + row * 144 + seg * 16) =
            *(const float4*)(srch + row * 128 + seg * 16);
        *(float4*)((char*)&blo[0][0] + row * 144 + seg * 16) =
            *(const float4*)(srcl + row * 128 + seg * 16);
      }
    }
    __syncthreads();

    for (int nt = 0; nt < 8; nt += 2) {
      const int cc0 = nt * 16 + ml;
      const int cc1 = cc0 + 16;
      const char* b0h = (const char*)&bhi[0][0] + cc0 * 144 + qd * 16;
      const char* b0l = (const char*)&blo[0][0] + cc0 * 144 + qd * 16;
      const char* b1h = (const char*)&bhi[0][0] + cc1 * 144 + qd * 16;
      const char* b1l = (const char*)&blo[0][0] + cc1 * 144 + qd * 16;
      short8 bh00 = *(const short8*)(b0h);
      short8 bh01 = *(const short8*)(b0h + 64);
      short8 bl00 = *(const short8*)(b0l);
      short8 bl01 = *(const short8*)(b0l + 64);
      short8 bh10 = *(const short8*)(b1h);
      short8 bh11 = *(const short8*)(b1h + 64);
      short8 bl10 = *(const short8*)(b1l);
      short8 bl11 = *(const short8*)(b1l + 64);

      f32x4 acc0 = {0.f, 0.f, 0.f, 0.f};
      f32x4 acc1 = {0.f, 0.f, 0.f, 0.f};
      acc0 = __builtin_amdgcn_mfma_f32_16x16x32_bf16(a_h0, bh00, acc0, 0, 0, 0);
      acc1 = __builtin_amdgcn_mfma_f32_16x16x32_bf16(a_h0, bh10, acc1, 0, 0, 0);
      acc0 = __builtin_amdgcn_mfma_f32_16x16x32_bf16(a_h1, bh01, acc0, 0, 0, 0);
      acc1 = __builtin_amdgcn_mfma_f32_16x16x32_bf16(a_h1, bh11, acc1, 0, 0, 0);
      acc0 = __builtin_amdgcn_mfma_f32_16x16x32_bf16(a_l0, bh00, acc0, 0, 0, 0);
      acc1 = __builtin_amdgcn_mfma_f32_16x16x32_bf16(a_l0, bh10, acc1, 0, 0, 0);
      acc0 = __builtin_amdgcn_mfma_f32_16x16x32_bf16(a_l1, bh01, acc0, 0, 0, 0);
      acc1 = __builtin_amdgcn_mfma_f32_16x16x32_bf16(a_l1, bh11, acc1, 0, 0, 0);
      acc0 = __builtin_amdgcn_mfma_f32_16x16x32_bf16(a_h0, bl00, acc0, 0, 0, 0);
      acc1 = __builtin_amdgcn_mfma_f32_16x16x32_bf16(a_h0, bl10, acc1, 0, 0, 0);
      acc0 = __builtin_amdgcn_mfma_f32_16x16x32_bf16(a_h1, bl01, acc0, 0, 0, 0);
      acc1 = __builtin_amdgcn_mfma_f32_16x16x32_bf16(a_h1, bl11, acc1, 0, 0, 0);

      const int j0 = c0 + nt * 16 + ml;
      const int j1 = j0 + 16;
      const float s0 = se_lds[j0];
      const float s1 = se_lds[j1];
      #pragma unroll
      for (int r = 0; r < 4; ++r) {
        float v0 = s0 - 2.f * acc0[r];
        if (v0 < bestv[r]) { secv[r] = bestv[r]; bestv[r] = v0; bestj[r] = j0; }
        else secv[r] = fminf(secv[r], v0);
        float v1 = s1 - 2.f * acc1[r];
        if (v1 < bestv[r]) { secv[r] = bestv[r]; bestv[r] = v1; bestj[r] = j1; }
        else secv[r] = fminf(secv[r], v1);
      }
    }
  }

  // ---- cross-lane merge within each 16-lane quad group ----
  #pragma unroll
  for (int off = 1; off < 16; off <<= 1) {
    #pragma unroll
    for (int r = 0; r < 4; ++r) {
      float ov = __shfl_xor(bestv[r], off, 16);
      float os = __shfl_xor(secv[r], off, 16);
      int   oj = __shfl_xor(bestj[r], off, 16);
      bool take = (ov < bestv[r]) || (ov == bestv[r] && oj < bestj[r]);
      float loser = take ? bestv[r] : ov;
      bestv[r] = take ? ov : bestv[r];
      bestj[r] = take ? oj : bestj[r];
      secv[r]  = fminf(fminf(loser, os), secv[r]);
    }
  }
  if (ml == 0) {
    #pragma unroll
    for (int r = 0; r < 4; ++r) {
      int m = wv * 16 + qd * 4 + r;
      tok_best[m] = bestv[r];
      tok_sec[m]  = secv[r];
      tok_idx[m]  = bestj[r];
    }
  }
  __syncthreads();

  if (tid < kTokPerBlk) {
    if (tok_sec[tid] - tok_best[tid] < kMargin) {
      int p = atomicAdd(&flag_cnt, 1);
      flag_list[p] = tid;
    }
  }
  __syncthreads();

  const int nflag = flag_cnt;
  for (int fi = 0; fi < nflag; ++fi) {
    const int tr = flag_list[fi];
    double db = 1e300; int dbj = 0;
    #pragma unroll 1
    for (int jj = 0; jj < 2; ++jj) {
      int j = tid * 2 + jj;
      const float* er = emb + (size_t)j * kED;
      double a0 = 0.0, a1 = 0.0, a2 = 0.0, a3 = 0.0;
      #pragma unroll
      for (int d = 0; d < kED; d += 4) {
        a0 = __builtin_fma((double)flat[tr][d+0], (double)er[d+0], a0);
        a1 = __builtin_fma((double)flat[tr][d+1], (double)er[d+1], a1);
        a2 = __builtin_fma((double)flat[tr][d+2], (double)er[d+2], a2);
        a3 = __builtin_fma((double)flat[tr][d+3], (double)er[d+3], a3);
      }
      double dist = se64[j] - 2.0 * ((a0 + a1) + (a2 + a3));
      if (dist < db || (dist == db && j < dbj)) { db = dist; dbj = j; }
    }
    redd[tid] = db; redj[tid] = dbj;
    __syncthreads();
    for (int s2 = kThreads / 2; s2 > 0; s2 >>= 1) {
      if (tid < s2) {
        double v = redd[tid + s2]; int j = redj[tid + s2];
        if (v < redd[tid] || (v == redd[tid] && j < redj[tid])) {
          redd[tid] = v; redj[tid] = j;
        }
      }
      __syncthreads();
    }
    if (tid == 0) tok_idx[tr] = redj[0];
    __syncthreads();
  }

  if (tid < kTokPerBlk) idx_out[token_base + tid] = tok_idx[tid];
  if (write_flat) {
    const int r  = tid >> 2;
    const int d0 = (tid & 3) * 16;
    float* dst = flat_ws + (size_t)(token_base + r) * kED + d0;
    #pragma unroll
    for (int i = 0; i < 4; ++i) {
      f32x4 v = {flat[r][d0 + i*4], flat[r][d0 + i*4 + 1],
                 flat[r][d0 + i*4 + 2], flat[r][d0 + i*4 + 3]};
      *(f32x4*)(dst + i * 4) = v;
    }
  }
}

// ---- counting sort for dw: hist -> scan -> scatter -> chunked seg-sum ----
extern "C" __global__ __launch_bounds__(kThreads) void vq_hist(
    const int* __restrict__ idx, int* __restrict__ parts) {
  __shared__ int h[kNE];
  const int tid = threadIdx.x, b = blockIdx.x;
  h[tid] = 0; h[tid + 256] = 0;
  __syncthreads();
  #pragma unroll
  for (int it = 0; it < 8; ++it)
    atomicAdd(&h[idx[b * 2048 + it * 256 + tid]], 1);
  __syncthreads();
  parts[b * kNE + tid] = h[tid];
  parts[b * kNE + tid + 256] = h[tid + 256];
}

extern "C" __global__ __launch_bounds__(512) void vq_scan(
    int* __restrict__ parts, int* __restrict__ start,
    float* __restrict__ cnt) {
  __shared__ int pl[64 * kNE];   // 128 KB
  __shared__ int sh[kNE];
  const int c = threadIdx.x;     // 0..511
  for (int i = c; i < 64 * kNE; i += 512) pl[i] = parts[i];
  __syncthreads();
  int run = 0;
  #pragma unroll 1
  for (int p = 0; p < 64; ++p) {
    int t = pl[p * kNE + c];
    pl[p * kNE + c] = run;
    run += t;
  }
  sh[c] = run;
  cnt[c] = (float)run;
  __syncthreads();
  #pragma unroll 1
  for (int off = 1; off < kNE; off <<= 1) {
    int t = (c >= off) ? sh[c - off] : 0;
    __syncthreads();
    sh[c] += t;
    __syncthreads();
  }
  int st = sh[c] - run;
  start[c] = st;
  #pragma unroll 1
  for (int p = 0; p < 64; ++p)
    parts[p * kNE + c] = st + pl[p * kNE + c];
}

// Writes PACKED entries: (code << 17) | token   (code<512, token<2^17)
extern "C" __global__ __launch_bounds__(kThreads) void vq_scatter(
    const int* __restrict__ idx, const int* __restrict__ parts,
    int* __restrict__ sorted) {
  __shared__ int cur[kNE];
  const int tid = threadIdx.x, b = blockIdx.x;
  cur[tid] = parts[b * kNE + tid];
  cur[tid + 256] = parts[b * kNE + tid + 256];
  __syncthreads();
  #pragma unroll
  for (int it = 0; it < 8; ++it) {
    int i = b * 2048 + it * 256 + tid;
    int c = idx[i];
    int pos = atomicAdd(&cur[c], 1);
    sorted[pos] = (c << 17) | i;
  }
}

// Load-balanced dw: 1024 blocks x 128 sorted tokens. Each wave owns a
// contiguous 32-token sub-range; lane d owns column d. Register run-
// accumulation over the (non-decreasing) code sequence; atomic flush on
// code change. Flush count <= 4*(chunks+clusters) regardless of skew.
extern "C" __global__ __launch_bounds__(kThreads) void vq_dw_chunk(
    const float* __restrict__ flat, const int* __restrict__ sorted,
    float* __restrict__ dwf) {
  __shared__ int spk[128];
  const int tid = threadIdx.x;
  const int base = blockIdx.x * 128;
  if (tid < 128) spk[tid] = sorted[base + tid];
  __syncthreads();
  const int tt = tid >> 6, d = tid & 63;
  int cur_c = -1;
  float acc = 0.f;
  #pragma unroll 1
  for (int bi = 0; bi < 8; ++bi) {
    int p = tt * 32 + bi * 4;
    int k0 = spk[p], k1 = spk[p + 1], k2 = spk[p + 2], k3 = spk[p + 3];
    // 4 independent coalesced row loads in flight together
    float v0 = flat[(size_t)(k0 & 131071) * kED + d];
    float v1 = flat[(size_t)(k1 & 131071) * kED + d];
    float v2 = flat[(size_t)(k2 & 131071) * kED + d];
    float v3 = flat[(size_t)(k3 & 131071) * kED + d];
    int c0 = k0 >> 17, c1 = k1 >> 17, c2 = k2 >> 17, c3 = k3 >> 17;
    if (c0 != cur_c) {   // wave-uniform branch (codes broadcast from LDS)
      if (cur_c >= 0) atomicAdd(&dwf[cur_c * kED + d], acc);
      acc = 0.f; cur_c = c0;
    }
    acc += v0;
    if (c1 != cur_c) { atomicAdd(&dwf[cur_c * kED + d], acc); acc = 0.f; cur_c = c1; }
    acc += v1;
    if (c2 != cur_c) { atomicAdd(&dwf[cur_c * kED + d], acc); acc = 0.f; cur_c = c2; }
    acc += v2;
    if (c3 != cur_c) { atomicAdd(&dwf[cur_c * kED + d], acc); acc = 0.f; cur_c = c3; }
    acc += v3;
  }
  atomicAdd(&dwf[cur_c * kED + d], acc);
}

// ---- streaming outputs ----
extern "C" __global__ __launch_bounds__(kThreads) void vq_enc(
    const int* __restrict__ idx, float* __restrict__ enc) {
  __shared__ int ti[kTokPerBlk];
  const int tid = threadIdx.x;
  const int token_base = blockIdx.x * kTokPerBlk;
  if (tid < kTokPerBlk) ti[tid] = idx[token_base + tid];
  __syncthreads();
  f32x2* encb2 = (f32x2*)(enc + (size_t)token_base * kNE);
  #pragma unroll 4
  for (int i = 0; i < 64; ++i) {
    int q = i * kThreads + tid;   // float2 idx, 0..16383
    int row = q >> 8;
    int c2  = (q & 255) * 2;
    int bi = ti[row];
    f32x2 v;
    v.x = (bi == c2)     ? 1.f : 0.f;
    v.y = (bi == c2 + 1) ? 1.f : 0.f;
    __builtin_nontemporal_store(v, &encb2[q]);
  }
}

extern "C" __global__ __launch_bounds__(kThreads) void vq_out(
    const float* __restrict__ x, const float* __restrict__ emb,
    const int* __restrict__ idx, float* __restrict__ out_q,
    float* __restrict__ loss_sum) {
  __shared__ float qt[kTokPerBlk * 65];
  __shared__ int ti[kTokPerBlk];
  __shared__ float lred[4];
  const int tid = threadIdx.x;
  const int token_base = blockIdx.x * kTokPerBlk;
  const int batch = token_base / kHW;
  const int pos0  = token_base % kHW;
  if (tid < kTokPerBlk) ti[tid] = idx[token_base + tid];
  __syncthreads();
  {
    int rr = tid >> 2;
    int c0 = (tid & 3) * 16;
    const float* er = emb + (size_t)ti[rr] * kED;
    #pragma unroll
    for (int i = 0; i < 4; ++i) {
      float4 v = *(const float4*)(er + c0 + i * 4);
      qt[rr * 65 + c0 + i * 4 + 0] = v.x;
      qt[rr * 65 + c0 + i * 4 + 1] = v.y;
      qt[rr * 65 + c0 + i * 4 + 2] = v.z;
      qt[rr * 65 + c0 + i * 4 + 3] = v.w;
    }
  }
  __syncthreads();
  float lacc = 0.f;
  {
    const float* xb = x + (size_t)batch * kED * kHW + pos0;
    float* outb = out_q + (size_t)batch * kED * kHW + pos0;
    const int p  = tid & 63;
    const int c0 = tid >> 6;
    #pragma unroll
    for (int i = 0; i < 16; ++i) {
      int c = i * 4 + c0;
      float inv  = xb[(size_t)c * kHW + p];
      float qv   = qt[p * 65 + c];
      float diff = qv - inv;
      __builtin_nontemporal_store(inv + diff, &outb[(size_t)c * kHW + p]);
      lacc = __builtin_fmaf(diff, diff, lacc);
    }
  }
  #pragma unroll
  for (int off = 32; off > 0; off >>= 1) lacc += __shfl_down(lacc, off, 64);
  if ((tid & 63) == 0) lred[tid >> 6] = lacc;
  __syncthreads();
  if (tid == 0)
    atomicAdd(loss_sum, (lred[0] + lred[1]) + (lred[2] + lred[3]));
}

// ---- fallback path (small ws): per-block LDS partials + dense reduce ----
extern "C" __global__ __launch_bounds__(kThreads) void vq_dw_part(
    const float* __restrict__ x, const int* __restrict__ idx,
    float* __restrict__ part, int G) {
  __shared__ float dwacc[kNE * kED];
  __shared__ int   hist[kNE];
  __shared__ float flat[kTokPerBlk][65];
  __shared__ int   idxs[kTokPerBlk];
  const int tid = threadIdx.x;
  #pragma unroll
  for (int i = 0; i < kNE * kED / kThreads; ++i) dwacc[i * kThreads + tid] = 0.f;
  for (int i = tid; i < kNE; i += kThreads) hist[i] = 0;
  __syncthreads();
  for (int tile = blockIdx.x; tile < kNTiles; tile += G) {
    const int token_base = tile * kTokPerBlk;
    const int batch = token_base / kHW;
    const int pos0  = token_base % kHW;
    const float* xb = x + (size_t)batch * kED * kHW + pos0;
    {
      const int p  = tid & 63;
      const int d0 = tid >> 6;
      #pragma unroll
      for (int i = 0; i < 16; ++i) {
        int d = i * 4 + d0;
        flat[p][d] = xb[(size_t)d * kHW + p];
      }
    }
    if (tid < kTokPerBlk) idxs[tid] = idx[token_base + tid];
    __syncthreads();
    {
      const int w = tid >> 6;
      const int d = tid & 63;
      #pragma unroll
      for (int i = 0; i < 16; ++i) {
        int rr = w + i * 4;
        atomicAdd(&dwacc[idxs[rr] * kED + d], flat[rr][d]);
      }
    }
    if (tid < kTokPerBlk) atomicAdd(&hist[idxs[tid]], 1);
    __syncthreads();
  }
  float* dst = part + (size_t)blockIdx.x * kPartStride;
  #pragma unroll
  for (int i = 0; i < kNE * kED / kThreads / 4; ++i) {
    int q = i * kThreads + tid;
    *(float4*)&dst[q * 4] = *(float4*)&dwacc[q * 4];
  }
  #pragma unroll
  for (int i = 0; i < kNE / kThreads; ++i) {
    int q = i * kThreads + tid;
    dst[kNE * kED + q] = (float)hist[q];
  }
}

extern "C" __global__ void vq_red(const float* __restrict__ part,
                                  float* __restrict__ dwf,
                                  float* __restrict__ cnt, int G) {
  int i = blockIdx.x * blockDim.x + threadIdx.x;
  if (i >= kPartStride) return;
  float s0 = 0.f, s1 = 0.f, s2 = 0.f, s3 = 0.f;
  int p = 0;
  for (; p + 3 < G; p += 4) {
    s0 += part[(size_t)(p + 0) * kPartStride + i];
    s1 += part[(size_t)(p + 1) * kPartStride + i];
    s2 += part[(size_t)(p + 2) * kPartStride + i];
    s3 += part[(size_t)(p + 3) * kPartStride + i];
  }
  for (; p < G; ++p) s0 += part[(size_t)p * kPartStride + i];
  float s = (s0 + s1) + (s2 + s3);
  if (i < kNE * kED) dwf[i] = s;
  else cnt[i - kNE * kED] = s;
}

extern "C" __global__ __launch_bounds__(kThreads) void vq_dw_atomic(
    const float* __restrict__ x, const int* __restrict__ idx,
    float* __restrict__ dwf, float* __restrict__ cnt) {
  __shared__ float flat[kTokPerBlk][65];
  __shared__ int   idxs[kTokPerBlk];
  const int tid = threadIdx.x;
  const int token_base = blockIdx.x * kTokPerBlk;
  const int batch = token_base / kHW;
  const int pos0  = token_base % kHW;
  const float* xb = x + (size_t)batch * kED * kHW + pos0;
  {
    const int p  = tid & 63;
    const int d0 = tid >> 6;
    #pragma unroll
    for (int i = 0; i < 16; ++i) {
      int d = i * 4 + d0;
      flat[p][d] = xb[(size_t)d * kHW + p];
    }
  }
  if (tid < kTokPerBlk) idxs[tid] = idx[token_base + tid];
  __syncthreads();
  {
    int rr = tid >> 2;
    int c0 = (tid & 3) * 16;
    float* dwr = dwf + (size_t)idxs[rr] * kED;
    #pragma unroll
    for (int i = 0; i < 16; ++i) atomicAdd(&dwr[c0 + i], flat[rr][c0 + i]);
  }
  if (tid < kTokPerBlk) atomicAdd(&cnt[idxs[tid]], 1.0f);
}

// cluster Laplace smoothing, perplexity, loss
extern "C" __global__ void vq_fin_a(const float* __restrict__ ema_cs,
                                    const float* __restrict__ counts,
                                    const float* __restrict__ loss_sum,
                                    float* __restrict__ out) {
  __shared__ float red[kNE];
  const int j = threadIdx.x;
  float craw = ema_cs[j] * 0.99f + 0.01f * counts[j];
  red[j] = craw;
  __syncthreads();
  for (int s = kNE / 2; s > 0; s >>= 1) {
    if (j < s) red[j] += red[j + s];
    __syncthreads();
  }
  float k = red[0];
  __syncthreads();
  float clu = (craw + 1e-5f) / (k + kNE * 1e-5f) * k;
  out[O_CLUSTER + j] = clu;
  float avg = counts[j] * (1.0f / 131072.0f);
  float term = avg * logf(avg + 1e-10f);
  red[j] = term;
  __syncthreads();
  for (int s = kNE / 2; s > 0; s >>= 1) {
    if (j < s) red[j] += red[j + s];
    __syncthreads();
  }
  if (j == 0) {
    out[O_PERP] = expf(-red[0]);
    out[O_LOSS] = 0.25f * loss_sum[0] * (1.0f / 8388608.0f);
  }
}

extern "C" __global__ void vq_fin_b(const float* __restrict__ ema_w,
                                    const float* __restrict__ dw,
                                    const float* __restrict__ out_cluster,
                                    float* __restrict__ out) {
  int i = blockIdx.x * blockDim.x + threadIdx.x;   // 0..32767
  int j = i >> 6;
  float nw = ema_w[i] * 0.99f + 0.01f * dw[i];
  out[O_NEWEMAW + i] = nw;
  out[O_NEWEMB + i] = nw / out_cluster[j];
}

extern "C" void kernel_launch(void* const* d_in, const int* in_sizes, int n_in,
                              void* d_out, int out_size, void* d_ws, size_t ws_size,
                              hipStream_t stream) {
  const float* x      = (const float*)d_in[0];
  const float* emb    = (const float*)d_in[1];
  const float* ema_w  = (const float*)d_in[2];
  const float* ema_cs = (const float*)d_in[3];
  float* out = (float*)d_out;
  float* ws  = (float*)d_ws;

  int*    idxb     = (int*)d_ws;
  float*  loss_sum = ws + F_LOSS;
  float*  se32     = ws + F_SE32;
  double* se64     = (double*)(ws + F_SE64);
  unsigned short* ehi = (unsigned short*)(ws + F_EHI);
  unsigned short* elo = (unsigned short*)(ws + F_ELO);
  float*  cnt      = ws + F_CNT;
  float*  dwf      = ws + F_DW;
  float*  aux      = ws + F_AUX;          // flat (token-major x) OR partials
  int*    parts    = (int*)(ws + F_EHI);  // reuse ehi+elo after argmin
  int*    startp   = (int*)(ws + F_SE32); // reuse se32 after argmin
  int*    sorted   = (int*)(out + O_ENC); // enc region scratch, overwritten by vq_enc

  const size_t need_flat = (F_AUX + (size_t)kNTok * kED) * 4;
  const bool flat_ok = ws_size >= need_flat;
  int G = 0;
  if (!flat_ok) {
    long avail = (long)(ws_size / 4) - (long)F_AUX;
    G = avail > 0 ? (int)(avail / kPartStride) : 0;
    if (G > 256) G = 256;
  }
  const bool part_ok = (G >= 8);

  hipMemsetAsync(ws + F_LOSS, 0, sizeof(float), stream);
  if (flat_ok) {
    hipMemsetAsync(ws + F_DW, 0, kNE * kED * sizeof(float), stream);
  } else if (!part_ok) {
    hipMemsetAsync(ws + F_CNT, 0, (kNE + kNE * kED) * sizeof(float), stream);
  }

  hipLaunchKernelGGL(vq_se2, dim3(2), dim3(256), 0, stream,
                     emb, se32, se64, ehi, elo);
  hipLaunchKernelGGL(vq_argmin, dim3(kNTiles), dim3(kThreads), 0, stream,
                     x, emb, se32, se64, ehi, elo, idxb, aux, flat_ok ? 1 : 0);
  if (flat_ok) {
    hipLaunchKernelGGL(vq_hist, dim3(64), dim3(kThreads), 0, stream,
                       idxb, parts);
    hipLaunchKernelGGL(vq_scan, dim3(1), dim3(512), 0, stream,
                       parts, startp, cnt);
    hipLaunchKernelGGL(vq_scatter, dim3(64), dim3(kThreads), 0, stream,
                       idxb, parts, sorted);
    hipLaunchKernelGGL(vq_dw_chunk, dim3(kNTok / 128), dim3(kThreads), 0, stream,
                       aux, sorted, dwf);
  } else if (part_ok) {
    hipLaunchKernelGGL(vq_dw_part, dim3(G), dim3(kThreads), 0, stream,
                       x, idxb, aux, G);
    hipLaunchKernelGGL(vq_red, dim3((kPartStride + 255) / 256), dim3(256), 0,
                       stream, aux, dwf, cnt, G);
  } else {
    hipLaunchKernelGGL(vq_dw_atomic, dim3(kNTiles), dim3(kThreads), 0, stream,
                       x, idxb, dwf, cnt);
  }
  hipLaunchKernelGGL(vq_enc, dim3(kNTiles), dim3(kThreads), 0, stream,
                     idxb, out + O_ENC);
  hipLaunchKernelGGL(vq_out, dim3(kNTiles), dim3(kThreads), 0, stream,
                     x, emb, idxb, out + O_OUT, loss_sum);
  hipLaunchKernelGGL(vq_fin_a, dim3(1), dim3(kNE), 0, stream,
                     ema_cs, cnt, loss_sum, out);
  hipLaunchKernelGGL(vq_fin_b, dim3(kNE * kED / 256), dim3(256), 0, stream,
                     ema_w, dwf, out + O_CLUSTER, out);
}